// Round 1
// baseline (248.979 us; speedup 1.0000x reference)
//
#include <hip/hip_runtime.h>

#define R_ROUNDS 64
#define HID 256
#define BATCH 16384
#define ROWS_PER_WAVE 4

// ---------------------------------------------------------------------------
// Pre-pass: pack ternary matrices (float -1/0/1) into GF(2) bitmasks.
// bit k of word w of row (r,j)  =  (M[r][j][32w+k] != 0)
// One wave covers 64 consecutive flat elements -> one __ballot -> 2 u32 words.
// Total packed size: 64*256*256 bits = 512 KB (lives in d_ws).
// ---------------------------------------------------------------------------
__global__ void pack_matrices_kernel(const float* __restrict__ M,
                                     unsigned int* __restrict__ P) {
    const int e    = blockIdx.x * blockDim.x + threadIdx.x;  // flat element idx
    const int lane = threadIdx.x & 63;
    const float v  = M[e];
    const unsigned long long m = __ballot(v != 0.0f);
    if (lane == 0) {
        const int w = e >> 5;                 // wave base /32 (even)
        P[w]     = (unsigned int)m;
        P[w + 1] = (unsigned int)(m >> 32);
    }
}

// ---------------------------------------------------------------------------
// Main recurrence. One wave owns ROWS_PER_WAVE batch rows.
// Lane l computes output bits j = 64*i + l (i = 0..3).
// Row state (256 bits) is held as 4 wave-uniform u64 ballot results (SGPRs):
//   S[row][i] bit l  =  state bit (64*i + l)   -> word 2i = lo32, 2i+1 = hi32.
// Per bit: parity(popc(s & A_j)) ^ noise_bit, then __ballot repacks the new
// state with no LDS and no cross-wave traffic.
// ---------------------------------------------------------------------------
__global__ __launch_bounds__(256) void tenshash_kernel(
        const float* __restrict__ state,
        const unsigned int* __restrict__ pA,
        const float* __restrict__ noise,
        float* __restrict__ out) {
    const int lane = threadIdx.x & 63;
    const int wave = (blockIdx.x * blockDim.x + threadIdx.x) >> 6;
    const int row0 = wave * ROWS_PER_WAVE;

    // ---- pack initial state from float bits ----
    unsigned long long S[ROWS_PER_WAVE][4];
#pragma unroll
    for (int rw = 0; rw < ROWS_PER_WAVE; ++rw) {
#pragma unroll
        for (int i = 0; i < 4; ++i) {
            const float v = state[(size_t)(row0 + rw) * HID + i * 64 + lane];
            S[rw][i] = __ballot(v != 0.0f);
        }
    }

    // ---- 64-round recurrence ----
#pragma unroll 1
    for (int r = 0; r < R_ROUNDS; ++r) {
        // A rows for this lane's bits: j = i*64 + lane, 8 u32 each (2x uint4).
        // 512 KB packed matrix is L2-resident -> these are L2 hits.
        uint4 a[4][2];
        const uint4* pa = (const uint4*)(pA + (size_t)r * HID * 8);
#pragma unroll
        for (int i = 0; i < 4; ++i) {
            a[i][0] = pa[(i * 64 + lane) * 2];
            a[i][1] = pa[(i * 64 + lane) * 2 + 1];
        }

        // Noise floats: perfectly coalesced (lane l -> element 64i+l).
        float nf[ROWS_PER_WAVE][4];
#pragma unroll
        for (int rw = 0; rw < ROWS_PER_WAVE; ++rw) {
            const float* np = noise + (size_t)(row0 + rw) * (R_ROUNDS * HID)
                                    + (size_t)r * HID;
#pragma unroll
            for (int i = 0; i < 4; ++i) nf[rw][i] = np[i * 64 + lane];
        }

        unsigned long long NS[ROWS_PER_WAVE][4];
#pragma unroll
        for (int rw = 0; rw < ROWS_PER_WAVE; ++rw) {
            const unsigned int s0 = (unsigned int)(S[rw][0]);
            const unsigned int s1 = (unsigned int)(S[rw][0] >> 32);
            const unsigned int s2 = (unsigned int)(S[rw][1]);
            const unsigned int s3 = (unsigned int)(S[rw][1] >> 32);
            const unsigned int s4 = (unsigned int)(S[rw][2]);
            const unsigned int s5 = (unsigned int)(S[rw][2] >> 32);
            const unsigned int s6 = (unsigned int)(S[rw][3]);
            const unsigned int s7 = (unsigned int)(S[rw][3] >> 32);
#pragma unroll
            for (int i = 0; i < 4; ++i) {
                unsigned int c = __popc(a[i][0].x & s0) + __popc(a[i][0].y & s1)
                               + __popc(a[i][0].z & s2) + __popc(a[i][0].w & s3)
                               + __popc(a[i][1].x & s4) + __popc(a[i][1].y & s5)
                               + __popc(a[i][1].z & s6) + __popc(a[i][1].w & s7)
                               + (unsigned int)nf[rw][i];   // exact: nf in {0.0,1.0}
                NS[rw][i] = __ballot((int)(c & 1u));
            }
        }
#pragma unroll
        for (int rw = 0; rw < ROWS_PER_WAVE; ++rw)
#pragma unroll
            for (int i = 0; i < 4; ++i) S[rw][i] = NS[rw][i];
    }

    // ---- unpack final state to float32 {0,1}, coalesced stores ----
#pragma unroll
    for (int rw = 0; rw < ROWS_PER_WAVE; ++rw) {
#pragma unroll
        for (int i = 0; i < 4; ++i) {
            const unsigned int bit = (unsigned int)((S[rw][i] >> lane) & 1ULL);
            out[(size_t)(row0 + rw) * HID + i * 64 + lane] = (float)bit;
        }
    }
}

extern "C" void kernel_launch(void* const* d_in, const int* in_sizes, int n_in,
                              void* d_out, int out_size, void* d_ws, size_t ws_size,
                              hipStream_t stream) {
    const float* state = (const float*)d_in[0];
    const float* mats  = (const float*)d_in[1];
    const float* noise = (const float*)d_in[2];
    float* out         = (float*)d_out;
    unsigned int* pA   = (unsigned int*)d_ws;   // 512 KB packed matrices

    const int n_m = R_ROUNDS * HID * HID;       // 4,194,304 elements
    pack_matrices_kernel<<<n_m / 256, 256, 0, stream>>>(mats, pA);

    const int waves  = BATCH / ROWS_PER_WAVE;   // 4096 waves
    const int blocks = waves / 4;               // 1024 blocks of 256 threads
    tenshash_kernel<<<blocks, 256, 0, stream>>>(state, pA, noise, out);
}